// Round 2
// baseline (321.390 us; speedup 1.0000x reference)
//
#include <hip/hip_runtime.h>
#include <hip/hip_bf16.h>

#define H  4096
#define V  4
#define OUT_N 4
#define MS 104
#define MD 3

// Block geometry for the fused GRU GEMV: 2 hidden indices per block,
// one wave per w_hh row (3 gates x 2 k = 6 waves = 384 threads).
#define KPB 2
#define TPB (KPB * 3 * 64)

__device__ __forceinline__ float b2f(unsigned short u) {
    return __uint_as_float(((unsigned int)u) << 16);
}
// Load element i of tensor p as float, interpreting storage per flag.
__device__ __forceinline__ float ldf(const void* p, size_t i, bool is_f32) {
    return is_f32 ? ((const float*)p)[i] : b2f(((const unsigned short*)p)[i]);
}
__device__ __forceinline__ void stf(void* p, size_t i, bool is_f32, float v) {
    if (is_f32) ((float*)p)[i] = v;
    else        ((__hip_bfloat16*)p)[i] = __float2bfloat16(v);
}

// ---------------------------------------------------------------------------
// Inline wave-uniform dtype detection. Decode first 1024 ushorts of w_hh as
// bf16: real bf16 weights are all |x| <~ 0.2; f32 storage puts random-exponent
// halves there (42%/elem chance of |x|>1e6) -> certain to trip over 1024
// samples. Ballot makes the result wave-uniform. 2 KB, L1/L2-hot after wave 0.
// ---------------------------------------------------------------------------
__device__ __forceinline__ bool detect_f32(const void* w_hh) {
    const unsigned short* w = (const unsigned short*)w_hh;
    const int lane = threadIdx.x & 63;
    int bad = 0;
    #pragma unroll
    for (int i = 0; i < 16; ++i) {
        const float v = b2f(w[lane + (i << 6)]);
        if (!(fabsf(v) < 1.0e6f)) bad = 1;   // catches inf/NaN bit patterns too
    }
    return __ballot(bad) != 0ull;
}

// 8 bf16 (as uint4) dotted against 8 f32 (two float4). Little-endian: low
// ushort of a.x is element 0 -> float is (u<<16); high ushort is (u&0xffff0000).
__device__ __forceinline__ float dot8(uint4 a, float4 h0, float4 h1) {
    return __uint_as_float(a.x << 16)          * h0.x
         + __uint_as_float(a.x & 0xffff0000u)  * h0.y
         + __uint_as_float(a.y << 16)          * h0.z
         + __uint_as_float(a.y & 0xffff0000u)  * h0.w
         + __uint_as_float(a.z << 16)          * h1.x
         + __uint_as_float(a.z & 0xffff0000u)  * h1.y
         + __uint_as_float(a.w << 16)          * h1.z
         + __uint_as_float(a.w & 0xffff0000u)  * h1.w;
}

// ---------------------------------------------------------------------------
// Fused h_bar + GRU GEMV.
// Stage 1: every block redundantly computes the FULL h_bar (H fp32) into LDS.
//   w_sh/b_sh/hidden0 = 80 KB, L2/L3-resident after the first block touches
//   them; numerics identical across blocks (deterministic).
// Stage 2: one WAVE per w_hh row (wave w -> gate g=w%3, kk=w/3): one
//   contiguous 16 KB (f32) / 8 KB (bf16) stream, dotted against LDS h_bar
//   with 16 B/lane vector loads, shuffle-reduced.
// Stage 3: threads t<KPB finish the GRU gates for their hidden index.
// 2048 blocks x 384 threads -> 12288 waves, ~30 waves/CU resident.
// ---------------------------------------------------------------------------
__global__ __launch_bounds__(TPB) void gru_fused_kernel(
    const int*  __restrict__ inp,  const void* __restrict__ emb,
    const void* __restrict__ w_ih, const void* __restrict__ w_hh,
    const void* __restrict__ b_ih, const void* __restrict__ b_hh,
    const void* __restrict__ w_sh, const void* __restrict__ b_sh,
    const void* __restrict__ hidden0, const void* __restrict__ stack,
    float* __restrict__ h_f32, void* __restrict__ out) {
    const bool f32 = detect_f32(w_hh);
    const int t = threadIdx.x;
    const int wave = t >> 6, lane = t & 63;
    const int k0 = blockIdx.x * KPB;

    __shared__ float hb_lds[H];
    __shared__ float red[KPB][3];

    // ---- Stage 1: full h_bar into LDS ------------------------------------
    const float s0 = ldf(stack, 0, f32);
    const float s1 = ldf(stack, 1, f32);
    const float s2 = ldf(stack, 2, f32);
    for (int j = t; j < H; j += TPB) {
        hb_lds[j] = ldf(w_sh, (size_t)j * 3 + 0, f32) * s0
                  + ldf(w_sh, (size_t)j * 3 + 1, f32) * s1
                  + ldf(w_sh, (size_t)j * 3 + 2, f32) * s2
                  + ldf(b_sh, j, f32) + ldf(hidden0, j, f32);
    }
    __syncthreads();

    // ---- Stage 2: one row-dot per wave ------------------------------------
    const int g  = wave % 3;          // 0=r, 1=z, 2=n (PyTorch gate order)
    const int kk = wave / 3;
    const int row = g * H + k0 + kk;

    float acc = 0.f;
    if (f32) {
        const float4* W  = (const float4*)w_hh + (size_t)row * (H / 4);
        const float4* HB = (const float4*)hb_lds;
        #pragma unroll 4
        for (int it = 0; it < H / 256; ++it) {        // 16 iters
            const int i = (it << 6) + lane;
            const float4 a = W[i], hb = HB[i];
            acc += a.x * hb.x + a.y * hb.y + a.z * hb.z + a.w * hb.w;
        }
    } else {
        const uint4*  W  = (const uint4*)w_hh + (size_t)row * (H / 8);
        const float4* HB = (const float4*)hb_lds;
        #pragma unroll 4
        for (int it = 0; it < H / 512; ++it) {        // 8 iters
            const int i = (it << 6) + lane;
            acc += dot8(W[i], HB[2 * i], HB[2 * i + 1]);
        }
    }
    #pragma unroll
    for (int off = 32; off > 0; off >>= 1) acc += __shfl_down(acc, off);
    if (lane == 0) red[kk][g] = acc;
    __syncthreads();

    // ---- Stage 3: finish gates for KPB hidden indices ---------------------
    if (t < KPB) {
        const int k = k0 + t;
        const float sr = red[t][0], sz = red[t][1], sn = red[t][2];

        const int idx = inp[0];
        float x[V];
        #pragma unroll
        for (int c = 0; c < V; ++c) x[c] = ldf(emb, (size_t)idx * V + c, f32);

        float gi[3];
        #pragma unroll
        for (int gg = 0; gg < 3; ++gg) {
            float a = ldf(b_ih, (size_t)(k + gg * H), f32);
            #pragma unroll
            for (int c = 0; c < V; ++c)
                a += ldf(w_ih, (size_t)(k + gg * H) * V + c, f32) * x[c];
            gi[gg] = a;
        }
        const float ghr = sr + ldf(b_hh, (size_t)k,           f32);
        const float ghz = sz + ldf(b_hh, (size_t)(k + H),     f32);
        const float ghn = sn + ldf(b_hh, (size_t)(k + 2 * H), f32);

        const float r = 1.f / (1.f + expf(-(gi[0] + ghr)));
        const float z = 1.f / (1.f + expf(-(gi[1] + ghz)));
        const float n = tanhf(gi[2] + r * ghn);
        const float hk = (1.f - z) * n + z * hb_lds[k];

        h_f32[k] = hk;
        stf(out, (size_t)(OUT_N + k), f32, hk);   // hidden output
    }
}

// ---------------------------------------------------------------------------
// Heads: one row-dot per WAVE (9 of 16 waves active), single barrier, then
// sigmoid/softmax + differentiable stack blend. 144 KB cold reads.
// ---------------------------------------------------------------------------
__global__ __launch_bounds__(1024) void heads_kernel(
    const float* __restrict__ h,
    const void* __restrict__ w_y, const void* __restrict__ b_y,
    const void* __restrict__ w_a, const void* __restrict__ b_a,
    const void* __restrict__ w_n, const void* __restrict__ b_n,
    const void* __restrict__ stack, const void* __restrict__ w_hh,
    void* __restrict__ out) {
    const bool f32 = detect_f32(w_hh);
    const int t = threadIdx.x, wave = t >> 6, lane = t & 63;

    __shared__ float scal[9];
    if (wave < 9) {
        const void* base; size_t row;
        if (wave < 4)      { base = w_y; row = (size_t)wave * H; }
        else if (wave < 6) { base = w_a; row = (size_t)(wave - 4) * H; }
        else               { base = w_n; row = (size_t)(wave - 6) * H; }

        float acc = 0.f;
        if (f32) {
            const float4* W  = (const float4*)((const float*)base + row);
            const float4* Hv = (const float4*)h;
            #pragma unroll 4
            for (int it = 0; it < H / 256; ++it) {
                const int i = (it << 6) + lane;
                const float4 a = W[i], hb = Hv[i];
                acc += a.x * hb.x + a.y * hb.y + a.z * hb.z + a.w * hb.w;
            }
        } else {
            const uint4*  W  = (const uint4*)((const unsigned short*)base + row);
            const float4* Hv = (const float4*)h;
            #pragma unroll 2
            for (int it = 0; it < H / 512; ++it) {
                const int i = (it << 6) + lane;
                acc += dot8(W[i], Hv[2 * i], Hv[2 * i + 1]);
            }
        }
        #pragma unroll
        for (int off = 32; off > 0; off >>= 1) acc += __shfl_down(acc, off);
        if (lane == 0) scal[wave] = acc;
    }
    __syncthreads();

    __shared__ float act0, act1, ne[MD];
    if (t == 0) {
        const float a0 = scal[4] + ldf(b_a, 0, f32);
        const float a1 = scal[5] + ldf(b_a, 1, f32);
        const float m  = fmaxf(a0, a1);
        const float e0 = expf(a0 - m), e1 = expf(a1 - m);
        const float inv = 1.f / (e0 + e1);
        act0 = e0 * inv; act1 = e1 * inv;
    }
    if (t < OUT_N)
        stf(out, (size_t)t, f32,
            1.f / (1.f + expf(-(scal[t] + ldf(b_y, t, f32)))));
    if (t < MD)
        ne[t] = 1.f / (1.f + expf(-(scal[6 + t] + ldf(b_n, t, f32))));
    __syncthreads();

    const float a0 = act0, a1 = act1;
    for (int idx = t; idx < MS * MD; idx += 1024) {
        const int i = idx / MD;
        const int d = idx - i * MD;
        const float push = (i == 0)      ? ne[d] : ldf(stack, (size_t)(idx - MD), f32);
        const float pop  = (i == MS - 1) ? 0.f   : ldf(stack, (size_t)(idx + MD), f32);
        stf(out, (size_t)(OUT_N + H + idx), f32, a0 * push + a1 * pop);
    }
}

extern "C" void kernel_launch(void* const* d_in, const int* in_sizes, int n_in,
                              void* d_out, int out_size, void* d_ws, size_t ws_size,
                              hipStream_t stream) {
    const int* inp      = (const int*)d_in[0];
    const void* hidden0 = d_in[1];
    const void* stack   = d_in[2];
    const void* emb     = d_in[3];
    const void* w_ih    = d_in[4];
    const void* w_hh    = d_in[5];
    const void* b_ih    = d_in[6];
    const void* b_hh    = d_in[7];
    const void* w_y     = d_in[8];
    const void* b_y     = d_in[9];
    const void* w_n     = d_in[10];
    const void* b_n     = d_in[11];
    const void* w_a     = d_in[12];
    const void* b_a     = d_in[13];
    const void* w_sh    = d_in[14];
    const void* b_sh    = d_in[15];

    float* h = (float*)d_ws;              // H fp32 (16 B aligned: hipMalloc)

    gru_fused_kernel<<<H / KPB, TPB, 0, stream>>>(
        inp, emb, w_ih, w_hh, b_ih, b_hh, w_sh, b_sh, hidden0, stack, h, d_out);
    heads_kernel<<<1, 1024, 0, stream>>>(h, w_y, b_y, w_a, b_a, w_n, b_n,
                                         stack, w_hh, d_out);
}